// Round 1
// 209.218 us; speedup vs baseline: 1.0739x; 1.0739x over previous
//
#include <hip/hip_runtime.h>

// GCN 2-layer: per layer h = X@W; out[i] = b + dinv[i]^2*h[i] + sum_{e:dst=i} dinv[src]*dinv[i]*h[src]
// N=100000 nodes, E=1200000 edges, C=64 channels.
// Kept: dinv[src] folded into gemm epilogue; dinv[dst] applied once in aggregate;
//       atomic-free multisplit CSR build (R9); bf16 H + bf16 inter-layer act (R10/11);
//       predicated batch-16 gather (R12: 49->36us, epochs are the bottleneck).
// R13: 2 nodes/wave (32-lane half, 4B/lane).
// R14: aggregate = ONE NODE PER 8-LANE GROUP (lane = 8 channels, 16B uint4 = the
//      G13 coalescing sweet spot; 8 lanes x 16B = full 128B row). Nodes/wave 2->8:
//      wave generations drop 4x, gather insts drop 4x (1KB fetched/inst), 16
//      outstanding dwordx4 per wave. VGPR ~64->~112 (occ 8->4 waves/SIMD) but
//      nodes-in-flight still doubles. R13 evidence: latency-epoch-bound.

#define NCH 64
#define XS_STRIDE 68   // 64 + 4 pad: keeps b128 16B alignment; 2-way conflicts only (free)
#define NBLK 256       // partition blocks; chunk = ceil(E/NBLK)
#define NBIN_MAX 512   // LDS array bound; runtime nbin = ceil(N/256) = 391

static __device__ __forceinline__ unsigned short f2bf(float f) {
    unsigned int u = __float_as_uint(f);
    unsigned int r = (u + 0x7FFFu + ((u >> 16) & 1u)) >> 16;  // round-to-nearest-even
    return (unsigned short)r;
}
static __device__ __forceinline__ float bf2f(unsigned short h) {
    return __uint_as_float(((unsigned int)h) << 16);
}

// ---------------- exclusive scan phases A/B (C folded into consumers) --------------
__global__ __launch_bounds__(256) void scanA_kernel(const int* __restrict__ counts,
                                                    int* __restrict__ outp,
                                                    int* __restrict__ bsums, int n) {
    __shared__ int sh[256];
    int tid = threadIdx.x;
    int base = blockIdx.x * 1024;
    int v[4];
    int ts = 0;
#pragma unroll
    for (int j = 0; j < 4; j++) {
        int idx = base + tid * 4 + j;
        int c = (idx < n) ? counts[idx] : 0;
        v[j] = c; ts += c;
    }
    sh[tid] = ts; __syncthreads();
    for (int off = 1; off < 256; off <<= 1) {
        int t = (tid >= off) ? sh[tid - off] : 0;
        __syncthreads();
        sh[tid] += t;
        __syncthreads();
    }
    int run = sh[tid] - ts;
#pragma unroll
    for (int j = 0; j < 4; j++) {
        run += v[j];
        int idx = base + tid * 4 + j;
        if (idx < n) outp[idx + 1] = run;   // within-chunk inclusive through idx
    }
    if (tid == 255) bsums[blockIdx.x] = sh[255];
}

__global__ __launch_bounds__(128) void scanB_kernel(int* __restrict__ bsums, int nb) {
    __shared__ int sh[128];
    int tid = threadIdx.x;
    int v = (tid < nb) ? bsums[tid] : 0;
    sh[tid] = v; __syncthreads();
    for (int off = 1; off < 128; off <<= 1) {
        int t = (tid >= off) ? sh[tid - off] : 0;
        __syncthreads();
        sh[tid] += t;
        __syncthreads();
    }
    if (tid < nb) bsums[tid] = sh[tid] - v;   // exclusive chunk offsets
}

// global exclusive prefix at idx, from scanA partials + scanB chunk offsets
static __device__ __forceinline__ int pref(const int* __restrict__ tscan,
                                           const int* __restrict__ bsums, int idx) {
    int c = idx >> 10, r = idx & 1023;
    int t = r ? tscan[idx] : 0;
    return bsums[c] + t;
}

// ---------------- phase 1: per-block bucket histogram (LDS only) ----------------
__global__ __launch_bounds__(256) void bhist_kernel(const int* __restrict__ dst,
                                                    int* __restrict__ table,
                                                    int E, int nbin) {
    __shared__ int hb[NBIN_MAX];
    int blk = blockIdx.x;
    for (int i = threadIdx.x; i < nbin; i += 256) hb[i] = 0;
    __syncthreads();
    int chunk = (E + NBLK - 1) / NBLK;
    int e0 = blk * chunk, e1 = min(e0 + chunk, E);
    for (int e = e0 + threadIdx.x; e < e1; e += 256)
        atomicAdd(&hb[dst[e] >> 8], 1);
    __syncthreads();
    for (int i = threadIdx.x; i < nbin; i += 256)
        table[i * NBLK + blk] = hb[i];   // bin-major: scan order = (bin, blk)
}

// ---------------- phase 3: ranked scatter into bucket-grouped 'binned' ----------
__global__ __launch_bounds__(256) void bscat_kernel(const int* __restrict__ src,
                                                    const int* __restrict__ dst,
                                                    const int* __restrict__ tscan,
                                                    const int* __restrict__ bsums,
                                                    unsigned int* __restrict__ binned,
                                                    int E, int nbin) {
    __shared__ int base[NBIN_MAX];
    __shared__ int cur[NBIN_MAX];
    int blk = blockIdx.x;
    for (int i = threadIdx.x; i < nbin; i += 256) {
        base[i] = pref(tscan, bsums, i * NBLK + blk);
        cur[i] = 0;
    }
    __syncthreads();
    int chunk = (E + NBLK - 1) / NBLK;
    int e0 = blk * chunk, e1 = min(e0 + chunk, E);
    for (int e = e0 + threadIdx.x; e < e1; e += 256) {
        int d = dst[e];
        int b = d >> 8;
        int r = atomicAdd(&cur[b], 1);   // LDS atomic, ~12 hits/address
        binned[base[b] + r] = ((unsigned int)(d & 255) << 24) | (unsigned int)src[e];
    }
}

// ---------------- phase 4: per-bucket fine pass -> rowp, dinv, csrc ----------------
__global__ __launch_bounds__(256) void bfine_kernel(const unsigned int* __restrict__ binned,
                                                    const int* __restrict__ tscan,
                                                    const int* __restrict__ bsums,
                                                    int* __restrict__ rowp,
                                                    float* __restrict__ dinv,
                                                    int* __restrict__ csrc,
                                                    int N, int nbin) {
    __shared__ int deg[256];
    __shared__ int sc[256];
    __shared__ int nodebase[256];
    int b = blockIdx.x;
    int nbase = b << 8;
    int nn = min(256, N - nbase);
    int tid = threadIdx.x;
    int bucket_base = pref(tscan, bsums, b * NBLK);
    int bucket_end  = pref(tscan, bsums, (b + 1) * NBLK);

    deg[tid] = 0;
    __syncthreads();
    for (int i = bucket_base + tid; i < bucket_end; i += 256)
        atomicAdd(&deg[binned[i] >> 24], 1);
    __syncthreads();
    int v = deg[tid];
    sc[tid] = v;
    __syncthreads();
    for (int off = 1; off < 256; off <<= 1) {
        int t = (tid >= off) ? sc[tid - off] : 0;
        __syncthreads();
        sc[tid] += t;
        __syncthreads();
    }
    int excl = sc[tid] - v;
    nodebase[tid] = bucket_base + excl;
    if (tid < nn) {
        rowp[nbase + tid] = bucket_base + excl;
        dinv[nbase + tid] = rsqrtf((float)(v + 1));  // +1 self loop
    }
    if (nbase + nn == N && tid == 255) rowp[N] = bucket_base + sc[255];
    deg[tid] = 0;                       // reuse as cursor
    __syncthreads();
    for (int i = bucket_base + tid; i < bucket_end; i += 256) {
        unsigned int u = binned[i];
        int ld = u >> 24;
        int pos = nodebase[ld] + atomicAdd(&deg[ld], 1);
        csrc[pos] = (int)(u & 0xFFFFFFu);
    }
}

// ---------------- H(bf16) = dinv ⊙ (X @ W)  (K=64, fp32 VALU) ----------------
// 64x64 tile per block; 256 threads as 16x16; each thread: 4 rows x 4 cols (16 acc).
// k-loop unroll capped at 2 (R4: full unroll -> 256 VGPR; R3: forced cap -> spills).
// X input fp32 (xbf16=0) or bf16 (xbf16=1, staged->fp32 LDS; inner loop identical).
__global__ __launch_bounds__(256) void gemm64_kernel(const void* __restrict__ Xv,
                                                     const float* __restrict__ W,
                                                     const float* __restrict__ dscale,
                                                     unsigned short* __restrict__ H,
                                                     int nrows, int xbf16) {
    __shared__ float Xs[64 * XS_STRIDE];
    __shared__ float Ws[64 * 64];
    int tid = threadIdx.x;
    int row0 = blockIdx.x * 64;

    {
        const float4* W4 = (const float4*)W;
#pragma unroll
        for (int i = 0; i < 4; i++) {
            int idx = tid + 256 * i;
            float4 v = W4[idx];
            int r = idx >> 4, kc = (idx & 15) << 2;
            *(float4*)&Ws[r * 64 + kc] = v;
        }
    }
    if (xbf16) {
        const unsigned short* Xh = (const unsigned short*)Xv + (size_t)row0 * NCH;
#pragma unroll
        for (int i = 0; i < 2; i++) {
            int idx = tid + 256 * i;      // 16B unit = 8 bf16 channels
            int r = idx >> 3, kc = (idx & 7) << 3;
            if (row0 + r < nrows) {
                int4 v = *(const int4*)&Xh[r * NCH + kc];
                float* dp = &Xs[r * XS_STRIDE + kc];
                float4 lo, hi;
                lo.x = bf2f((unsigned short)((unsigned)v.x & 0xFFFF));
                lo.y = bf2f((unsigned short)((unsigned)v.x >> 16));
                lo.z = bf2f((unsigned short)((unsigned)v.y & 0xFFFF));
                lo.w = bf2f((unsigned short)((unsigned)v.y >> 16));
                hi.x = bf2f((unsigned short)((unsigned)v.z & 0xFFFF));
                hi.y = bf2f((unsigned short)((unsigned)v.z >> 16));
                hi.z = bf2f((unsigned short)((unsigned)v.w & 0xFFFF));
                hi.w = bf2f((unsigned short)((unsigned)v.w >> 16));
                *(float4*)&dp[0] = lo;     // (r*68+kc)%4==0 -> 16B aligned
                *(float4*)&dp[4] = hi;
            }
        }
    } else {
        const float4* X4 = (const float4*)((const float*)Xv + (size_t)row0 * NCH);
#pragma unroll
        for (int i = 0; i < 4; i++) {
            int idx = tid + 256 * i;
            int r = idx >> 4, kc = (idx & 15) << 2;
            if (row0 + r < nrows)
                *(float4*)&Xs[r * XS_STRIDE + kc] = X4[idx];
        }
    }
    __syncthreads();

    int c  = (tid & 15) << 2;
    int r0 = (tid >> 4) << 2;

    float4 acc[4];
#pragma unroll
    for (int i = 0; i < 4; i++) acc[i] = make_float4(0.f, 0.f, 0.f, 0.f);

#pragma unroll 2
    for (int k4 = 0; k4 < 16; k4++) {
        float4 wv[4], xv[4];
#pragma unroll
        for (int j = 0; j < 4; j++) wv[j] = *(const float4*)&Ws[(k4 * 4 + j) * 64 + c];
#pragma unroll
        for (int i = 0; i < 4; i++) xv[i] = *(const float4*)&Xs[(r0 + i) * XS_STRIDE + k4 * 4];
#pragma unroll
        for (int i = 0; i < 4; i++) {
            acc[i].x += xv[i].x * wv[0].x + xv[i].y * wv[1].x + xv[i].z * wv[2].x + xv[i].w * wv[3].x;
            acc[i].y += xv[i].x * wv[0].y + xv[i].y * wv[1].y + xv[i].z * wv[2].y + xv[i].w * wv[3].y;
            acc[i].z += xv[i].x * wv[0].z + xv[i].y * wv[1].z + xv[i].z * wv[2].z + xv[i].w * wv[3].z;
            acc[i].w += xv[i].x * wv[0].w + xv[i].y * wv[1].w + xv[i].z * wv[2].w + xv[i].w * wv[3].w;
        }
    }

#pragma unroll
    for (int i = 0; i < 4; i++) {
        int row = row0 + r0 + i;
        if (row < nrows) {
            float ds = dscale[row];
            ushort4 o;
            o.x = f2bf(acc[i].x * ds);
            o.y = f2bf(acc[i].y * ds);
            o.z = f2bf(acc[i].z * ds);
            o.w = f2bf(acc[i].w * ds);
            *(ushort4*)&H[(size_t)row * NCH + c] = o;   // 8 B aligned (c%4==0)
        }
    }
}

// ---------------- gather-aggregate: ONE NODE PER 8-LANE GROUP ------------------
// lane = 8 channels (16B uint4; 8 lanes x 16B = full 128B bf16 row). Batch-16
// predicated slots per group (deg<=16: one csrc-epoch + one H-epoch). 8 nodes per
// wave -> 4x fewer wave generations than R13; each gather inst fetches 1KB.
// mode 0: write fp32 to outf. mode 1: relu + write bf16 to outh.
__global__ __launch_bounds__(256) void aggregate_kernel(const unsigned short* __restrict__ H,
                                                        const int* __restrict__ rowp,
                                                        const int* __restrict__ csrc,
                                                        const float* __restrict__ dinv,
                                                        const float* __restrict__ bias,
                                                        float* __restrict__ outf,
                                                        unsigned short* __restrict__ outh,
                                                        int n, int mode) {
    int node = blockIdx.x * 32 + (threadIdx.x >> 3);   // 32 nodes per 256-thread block
    int lane = threadIdx.x & 7;
    if (node >= n) return;
    int cb = lane << 3;          // channel base: 8 channels = 16B of bf16 per lane

    int e0  = rowp[node];
    int end = rowp[node + 1];
    // self row — issued before the edge loop, overlaps csrc fetch
    uint4 us = *(const uint4*)&H[(size_t)node * NCH + cb];
    float acc0 = bf2f((unsigned short)(us.x & 0xFFFFu));
    float acc1 = bf2f((unsigned short)(us.x >> 16));
    float acc2 = bf2f((unsigned short)(us.y & 0xFFFFu));
    float acc3 = bf2f((unsigned short)(us.y >> 16));
    float acc4 = bf2f((unsigned short)(us.z & 0xFFFFu));
    float acc5 = bf2f((unsigned short)(us.z >> 16));
    float acc6 = bf2f((unsigned short)(us.w & 0xFFFFu));
    float acc7 = bf2f((unsigned short)(us.w >> 16));

    int last = end - 1;          // valid when end > e0 (loop guard covers deg==0)
    for (int base = e0; base < end; base += 16) {
        int s[16];
#pragma unroll
        for (int k = 0; k < 16; k++)
            s[k] = csrc[min(base + k, last)];
        uint4 u[16];
#pragma unroll
        for (int k = 0; k < 16; k++)
            u[k] = *(const uint4*)&H[(size_t)s[k] * NCH + cb];
#pragma unroll
        for (int k = 0; k < 16; k++) {
            bool ok = (base + k < end);
            acc0 += ok ? bf2f((unsigned short)(u[k].x & 0xFFFFu)) : 0.f;
            acc1 += ok ? bf2f((unsigned short)(u[k].x >> 16)) : 0.f;
            acc2 += ok ? bf2f((unsigned short)(u[k].y & 0xFFFFu)) : 0.f;
            acc3 += ok ? bf2f((unsigned short)(u[k].y >> 16)) : 0.f;
            acc4 += ok ? bf2f((unsigned short)(u[k].z & 0xFFFFu)) : 0.f;
            acc5 += ok ? bf2f((unsigned short)(u[k].z >> 16)) : 0.f;
            acc6 += ok ? bf2f((unsigned short)(u[k].w & 0xFFFFu)) : 0.f;
            acc7 += ok ? bf2f((unsigned short)(u[k].w >> 16)) : 0.f;
        }
    }

    float di = dinv[node];
    float4 bv0 = *(const float4*)&bias[cb];
    float4 bv1 = *(const float4*)&bias[cb + 4];
    float o0 = bv0.x + di * acc0;
    float o1 = bv0.y + di * acc1;
    float o2 = bv0.z + di * acc2;
    float o3 = bv0.w + di * acc3;
    float o4 = bv1.x + di * acc4;
    float o5 = bv1.y + di * acc5;
    float o6 = bv1.z + di * acc6;
    float o7 = bv1.w + di * acc7;
    if (mode) {                        // relu + bf16 activation
        o0 = fmaxf(o0, 0.f); o1 = fmaxf(o1, 0.f);
        o2 = fmaxf(o2, 0.f); o3 = fmaxf(o3, 0.f);
        o4 = fmaxf(o4, 0.f); o5 = fmaxf(o5, 0.f);
        o6 = fmaxf(o6, 0.f); o7 = fmaxf(o7, 0.f);
        uint4 pk;
        pk.x = (unsigned int)f2bf(o0) | ((unsigned int)f2bf(o1) << 16);
        pk.y = (unsigned int)f2bf(o2) | ((unsigned int)f2bf(o3) << 16);
        pk.z = (unsigned int)f2bf(o4) | ((unsigned int)f2bf(o5) << 16);
        pk.w = (unsigned int)f2bf(o6) | ((unsigned int)f2bf(o7) << 16);
        *(uint4*)&outh[(size_t)node * NCH + cb] = pk;
    } else {
        *(float4*)&outf[(size_t)node * NCH + cb]     = make_float4(o0, o1, o2, o3);
        *(float4*)&outf[(size_t)node * NCH + cb + 4] = make_float4(o4, o5, o6, o7);
    }
}

extern "C" void kernel_launch(void* const* d_in, const int* in_sizes, int n_in,
                              void* d_out, int out_size, void* d_ws, size_t ws_size,
                              hipStream_t stream) {
    const float* x  = (const float*)d_in[0];
    const int* edge = (const int*)d_in[1];
    const float* W1 = (const float*)d_in[2];
    const float* b1 = (const float*)d_in[3];
    const float* W2 = (const float*)d_in[4];
    const float* b2 = (const float*)d_in[5];
    float* out = (float*)d_out;

    const int N = in_sizes[0] / NCH;       // 100000
    const int E = in_sizes[1] / 2;         // 1200000
    const int* src = edge;
    const int* dst = edge + E;

    const int nbin = (N + 255) >> 8;       // 391
    const int NT   = nbin * NBLK;          // 100096 table entries

    // workspace layout (16B-aligned blocks); every word used is written each call.
    char* w = (char*)d_ws;
    const size_t SZT = 401408;             // >= (NT+1)*4
    const size_t SZN = 400896;             // >= (N+1)*4
    int*   table  = (int*)(w + 0);                 // NT ints
    int*   tscan  = (int*)(w + SZT);               // NT+1 ints
    int*   rowp   = (int*)(w + 2 * SZT);           // N+1 ints
    float* dinv   = (float*)(w + 2 * SZT + SZN);   // N floats
    int*   bsums  = (int*)(w + 2 * SZT + 2 * SZN); // 128 ints
    unsigned int* binned = (unsigned int*)(w + 2 * SZT + 2 * SZN + 512);   // E uints
    int*   csrc   = (int*)(w + 2 * SZT + 2 * SZN + 512 + (size_t)E * 4);   // E ints
    unsigned short* h   = (unsigned short*)(w + 2 * SZT + 2 * SZN + 512 + (size_t)E * 8); // N*64 bf16
    unsigned short* act = h + (size_t)N * NCH;                             // N*64 bf16

    const int NB_SCAN_T = (NT + 1023) / 1024;   // 98

    // CSR build (atomic-free at global scope; scanC folded into bscat/bfine)
    bhist_kernel<<<NBLK, 256, 0, stream>>>(dst, table, E, nbin);
    scanA_kernel<<<NB_SCAN_T, 256, 0, stream>>>(table, tscan, bsums, NT);
    scanB_kernel<<<1, 128, 0, stream>>>(bsums, NB_SCAN_T);
    bscat_kernel<<<NBLK, 256, 0, stream>>>(src, dst, tscan, bsums, binned, E, nbin);
    bfine_kernel<<<nbin, 256, 0, stream>>>(binned, tscan, bsums, rowp, dinv, csrc, N, nbin);

    const int GB = (N + 63) / 64;      // gemm blocks (64 rows each)
    const int AB = (N + 31) / 32;      // aggregate blocks (32 nodes/block, 8 lanes/node)

    // Layer 1: h = bf16(dinv ⊙ (x@W1)) ; act = bf16(relu(b1 + dinv ⊙ gather-sum(h)))
    gemm64_kernel<<<GB, 256, 0, stream>>>(x, W1, dinv, h, N, 0);
    aggregate_kernel<<<AB, 256, 0, stream>>>(h, rowp, csrc, dinv, b1, nullptr, act, N, 1);
    // Layer 2: h = bf16(dinv ⊙ (act@W2)) ; d_out = b2 + dinv ⊙ gather-sum(h)  (fp32)
    gemm64_kernel<<<GB, 256, 0, stream>>>(act, W2, dinv, h, N, 1);
    aggregate_kernel<<<AB, 256, 0, stream>>>(h, rowp, csrc, dinv, b2, out, nullptr, N, 0);
}